// Round 8
// baseline (134.840 us; speedup 1.0000x reference)
//
#include <hip/hip_runtime.h>

// PointNetKnnInterpolator on MI355X (gfx950).
// h = [x[x_idx], pos_x[x_idx]-pos_y[y_idx]]  (400000 x 67)
// net = relu(h)@W0a+b0a ; dx = relu(net)@W1a+b1a ; h2 = h@Wsa + dx
// net2 = relu(h2)@W0b+b0b ; h3 = h2 + relu(net2)@W1b+b1b
// out[y] = max over 8 consecutive rows of h3.
//
// R8: R6 (stride partition, M=32 pairing, VGPR discipline) + gather/VALU cuts:
//   - prep_x: x pre-converted to f16 in d_ws (2.5 MB, L2-resident) ->
//     main-loop gather is one 16B dwordx4 straight into the A-frag, no cvts.
//   - prep_diff: (pos_x[xi]-pos_y[yi]) pre-computed as f16x4 (3.2 MB) ->
//     one 8B load on q==0 instead of 6 scalar loads + cvts.
//   - depth-2 pipeline: x_idx for pr+2, x-rows/diff for pr+1 issued before
//     compute; idx->row dependency never stalls the MFMA chain.
// R7 lesson: contiguous partition hurt L2 gather locality (FETCH +5MB) -> keep
// stride partition. LDS 68.6KB -> 2 blocks/CU = 16 waves/CU.

typedef _Float16 f16x8 __attribute__((ext_vector_type(8)));
typedef _Float16 f16x4 __attribute__((ext_vector_type(4)));
typedef float    f32x4 __attribute__((ext_vector_type(4)));

constexpr int NX      = 20000;
constexpr int NROWS   = 50000 * 8;   // NY * K
constexpr int NPAIRS  = NROWS / 32;  // 12500 (32 rows per wave-iteration)
constexpr int NFRAG   = 48;          // 12 W0a + 8 W1a + 12 Wsa + 8 W0b + 8 W1b
constexpr int TSTRIDE = 72;          // halves per row of transition buffer
constexpr int BW      = 8;           // waves per block (block = 512)
constexpr size_t X16_BYTES = (size_t)NX * 64 * 2;   // 2.56 MB

__global__ void prep_x(const float* __restrict__ x, _Float16* __restrict__ x16) {
    const int i = blockIdx.x * blockDim.x + threadIdx.x;   // one float4 each
    if (i < NX * 16) {
        float4 v = ((const float4*)x)[i];
        f16x4 o = {(_Float16)v.x, (_Float16)v.y, (_Float16)v.z, (_Float16)v.w};
        *(f16x4*)(x16 + (size_t)i * 4) = o;
    }
}

__global__ void prep_diff(const int* __restrict__ x_idx,
                          const float* __restrict__ px, const float* __restrict__ py,
                          _Float16* __restrict__ d16) {
    const int r = blockIdx.x * blockDim.x + threadIdx.x;
    if (r < NROWS) {
        const int xi = x_idx[r];
        const int yi = r >> 3;
        f16x4 o = {(_Float16)(px[xi * 3 + 0] - py[yi * 3 + 0]),
                   (_Float16)(px[xi * 3 + 1] - py[yi * 3 + 1]),
                   (_Float16)(px[xi * 3 + 2] - py[yi * 3 + 2]),
                   (_Float16)0};
        *(f16x4*)(d16 + (size_t)r * 4) = o;
    }
}

// write relu(acc[4]+bias[4]) in C-layout to tbuf, read back two A-fragments.
static __device__ __forceinline__ void xpose_relu(const f32x4* acc, const float* bb,
                                                  _Float16* tbuf, int q, int n0,
                                                  f16x8* af) {
    __threadfence_block();
#pragma unroll
    for (int t = 0; t < 4; ++t)
#pragma unroll
        for (int r = 0; r < 4; ++r) {
            float v = acc[t][r] + bb[t];
            tbuf[(q * 4 + r) * TSTRIDE + t * 16 + n0] = (_Float16)(v > 0.0f ? v : 0.0f);
        }
    __threadfence_block();
#pragma unroll
    for (int s = 0; s < 2; ++s)
        af[s] = *(const f16x8*)&tbuf[n0 * TSTRIDE + s * 32 + q * 8];
}

__global__ __launch_bounds__(512, 4)
void pointnet_fused(const _Float16* __restrict__ x16,
                    const _Float16* __restrict__ d16,
                    const int*   __restrict__ x_idx,
                    const float* __restrict__ W0a, const float* __restrict__ b0a,
                    const float* __restrict__ W1a, const float* __restrict__ b1a,
                    const float* __restrict__ Wsa,
                    const float* __restrict__ W0b, const float* __restrict__ b0b,
                    const float* __restrict__ W1b, const float* __restrict__ b1b,
                    float* __restrict__ out)
{
    __shared__ __align__(16) _Float16 bfrag[NFRAG * 64 * 8];       // 48 KiB
    __shared__ __align__(16) _Float16 trans[BW][16 * TSTRIDE];     // 18 KiB
    __shared__ float bias_lds[4 * 64];                             // 1 KiB

    const int tid = threadIdx.x;

    // ---- expand weights into B-fragment order (once per block) ----
    for (int p = tid; p < NFRAG * 64; p += 512) {
        const int f = p >> 6;
        const int l = p & 63;
        const float* W; int krows, fl;
        if (f < 12)      { W = W0a; krows = 67; fl = f; }
        else if (f < 20) { W = W1a; krows = 64; fl = f - 12; }
        else if (f < 32) { W = Wsa; krows = 67; fl = f - 20; }
        else if (f < 40) { W = W0b; krows = 64; fl = f - 32; }
        else             { W = W1b; krows = 64; fl = f - 40; }
        const int s = fl >> 2, t = fl & 3;
        const int n = t * 16 + (l & 15);
        const int kbase = s * 32 + (l >> 4) * 8;
        f16x8 v;
#pragma unroll
        for (int j = 0; j < 8; ++j) {
            const int k = kbase + j;
            v[j] = (_Float16)((k < krows) ? W[k * 64 + n] : 0.0f);
        }
        *(f16x8*)&bfrag[p * 8] = v;
    }
    if (tid < 256) {
        const int L = tid >> 6, i = tid & 63;
        const float* b = (L == 0) ? b0a : (L == 1) ? b1a : (L == 2) ? b0b : b1b;
        bias_lds[tid] = b[i];
    }
    __syncthreads();

    const int lane = tid & 63;
    const int wv   = tid >> 6;
    const int n0   = lane & 15;   // C col / A row m
    const int q    = lane >> 4;   // quad

    _Float16* tbuf = trans[wv];
    const int gwave  = blockIdx.x * BW + wv;
    const int nwaves = gridDim.x * BW;
    const int last   = ((NPAIRS - 1 - gwave) / nwaves) * nwaves + gwave; // last pr

    // ---- software pipeline: idx depth-2, row-data depth-1 ----
    f16x8 cra[2][2];   // prefetched x rows (f16) for current pr
    f16x4 crd[2];      // prefetched diff (q==0 lanes)
    int   xin[2];      // x_idx for NEXT pr

#pragma unroll
    for (int u = 0; u < 2; ++u) {
        const int row = gwave * 32 + u * 16 + n0;
        const int xi  = x_idx[row];
        const _Float16* xp = x16 + (long)xi * 64 + q * 8;
        cra[u][0] = *(const f16x8*)(xp);
        cra[u][1] = *(const f16x8*)(xp + 32);
        crd[u] = (f16x4){0, 0, 0, 0};
        if (q == 0) crd[u] = *(const f16x4*)(d16 + (long)row * 4);
    }
    {
        const int prn = (gwave + nwaves <= last) ? gwave + nwaves : last;
#pragma unroll
        for (int u = 0; u < 2; ++u)
            xin[u] = x_idx[prn * 32 + u * 16 + n0];
    }

    for (int pr = gwave; pr < NPAIRS; pr += nwaves) {
        // ---- consume prefetched A-side ----
        f16x8 hn[2][3];
#pragma unroll
        for (int u = 0; u < 2; ++u) {
            hn[u][0] = cra[u][0];
            hn[u][1] = cra[u][1];
            f16x8 z = {};
            hn[u][2] = z;
            if (q == 0) {
                hn[u][2][0] = crd[u][0];
                hn[u][2][1] = crd[u][1];
                hn[u][2][2] = crd[u][2];
            }
        }

        // ---- issue prefetch: rows/diff for pr+1 (idx already here), idx for pr+2 ----
        {
            const int prn = (pr + nwaves <= last) ? pr + nwaves : last;
#pragma unroll
            for (int u = 0; u < 2; ++u) {
                const _Float16* xp = x16 + (long)xin[u] * 64 + q * 8;
                cra[u][0] = *(const f16x8*)(xp);
                cra[u][1] = *(const f16x8*)(xp + 32);
                if (q == 0) crd[u] = *(const f16x4*)(d16 + (long)(prn * 32 + u * 16 + n0) * 4);
            }
            const int prn2 = (prn + nwaves <= last) ? prn + nwaves : last;
#pragma unroll
            for (int u = 0; u < 2; ++u)
                xin[u] = x_idx[prn2 * 32 + u * 16 + n0];
        }

        // ---- mm3 FIRST: A2 = h @ Wsa  (raw hn; frags 20..31) ----
        f32x4 A2[2][4];
#pragma unroll
        for (int u = 0; u < 2; ++u)
#pragma unroll
            for (int t = 0; t < 4; ++t)
                A2[u][t] = (f32x4){0.f, 0.f, 0.f, 0.f};
#pragma unroll
        for (int s = 0; s < 3; ++s)
#pragma unroll
            for (int t = 0; t < 4; ++t) {
                f16x8 b = *(const f16x8*)&bfrag[((20 + s * 4 + t) * 64 + lane) * 8];
                A2[0][t] = __builtin_amdgcn_mfma_f32_16x16x32_f16(hn[0][s], b, A2[0][t], 0, 0, 0);
                A2[1][t] = __builtin_amdgcn_mfma_f32_16x16x32_f16(hn[1][s], b, A2[1][t], 0, 0, 0);
            }

        // ---- relu hn IN PLACE, then mm1: A1 = relu(h) @ W0a (frags 0..11) ----
#pragma unroll
        for (int u = 0; u < 2; ++u)
#pragma unroll
            for (int s = 0; s < 3; ++s)
#pragma unroll
                for (int j = 0; j < 8; ++j) {
                    _Float16 v = hn[u][s][j];
                    hn[u][s][j] = v > (_Float16)0 ? v : (_Float16)0;
                }

        f32x4 A1[2][4];
#pragma unroll
        for (int u = 0; u < 2; ++u)
#pragma unroll
            for (int t = 0; t < 4; ++t)
                A1[u][t] = (f32x4){0.f, 0.f, 0.f, 0.f};
#pragma unroll
        for (int s = 0; s < 3; ++s)
#pragma unroll
            for (int t = 0; t < 4; ++t) {
                f16x8 b = *(const f16x8*)&bfrag[((s * 4 + t) * 64 + lane) * 8];
                A1[0][t] = __builtin_amdgcn_mfma_f32_16x16x32_f16(hn[0][s], b, A1[0][t], 0, 0, 0);
                A1[1][t] = __builtin_amdgcn_mfma_f32_16x16x32_f16(hn[1][s], b, A1[1][t], 0, 0, 0);
            }

        // ---- transpose relu(A1 + b0a) -> a2 frags; mm2: A2 += a2 @ W1a ----
        float bb[4];
#pragma unroll
        for (int t = 0; t < 4; ++t) bb[t] = bias_lds[0 * 64 + t * 16 + n0];
        f16x8 a2[2][2];
        xpose_relu(A1[0], bb, tbuf, q, n0, a2[0]);
        xpose_relu(A1[1], bb, tbuf, q, n0, a2[1]);
#pragma unroll
        for (int s = 0; s < 2; ++s)
#pragma unroll
            for (int t = 0; t < 4; ++t) {
                f16x8 b = *(const f16x8*)&bfrag[((12 + s * 4 + t) * 64 + lane) * 8];
                A2[0][t] = __builtin_amdgcn_mfma_f32_16x16x32_f16(a2[0][s], b, A2[0][t], 0, 0, 0);
                A2[1][t] = __builtin_amdgcn_mfma_f32_16x16x32_f16(a2[1][s], b, A2[1][t], 0, 0, 0);
            }

        // ---- A2 += b1a (h2 complete); transpose relu(A2) -> a4 ----
#pragma unroll
        for (int t = 0; t < 4; ++t) bb[t] = bias_lds[1 * 64 + t * 16 + n0];
#pragma unroll
        for (int u = 0; u < 2; ++u)
#pragma unroll
            for (int t = 0; t < 4; ++t)
#pragma unroll
                for (int r = 0; r < 4; ++r)
                    A2[u][t][r] += bb[t];
        const float bz[4] = {0.f, 0.f, 0.f, 0.f};
        f16x8 a4[2][2];
        xpose_relu(A2[0], bz, tbuf, q, n0, a4[0]);
        xpose_relu(A2[1], bz, tbuf, q, n0, a4[1]);

        // ---- mm4: A3 = a4 @ W0b (frags 32..39) ----
        f32x4 A3[2][4];
#pragma unroll
        for (int u = 0; u < 2; ++u)
#pragma unroll
            for (int t = 0; t < 4; ++t)
                A3[u][t] = (f32x4){0.f, 0.f, 0.f, 0.f};
#pragma unroll
        for (int s = 0; s < 2; ++s)
#pragma unroll
            for (int t = 0; t < 4; ++t) {
                f16x8 b = *(const f16x8*)&bfrag[((32 + s * 4 + t) * 64 + lane) * 8];
                A3[0][t] = __builtin_amdgcn_mfma_f32_16x16x32_f16(a4[0][s], b, A3[0][t], 0, 0, 0);
                A3[1][t] = __builtin_amdgcn_mfma_f32_16x16x32_f16(a4[1][s], b, A3[1][t], 0, 0, 0);
            }

        // ---- transpose relu(A3 + b0b) -> a5; mm5: A2 += b1b + a5 @ W1b ----
#pragma unroll
        for (int t = 0; t < 4; ++t) bb[t] = bias_lds[2 * 64 + t * 16 + n0];
        f16x8 a5[2][2];
        xpose_relu(A3[0], bb, tbuf, q, n0, a5[0]);
        xpose_relu(A3[1], bb, tbuf, q, n0, a5[1]);

#pragma unroll
        for (int t = 0; t < 4; ++t) bb[t] = bias_lds[3 * 64 + t * 16 + n0];
#pragma unroll
        for (int u = 0; u < 2; ++u)
#pragma unroll
            for (int t = 0; t < 4; ++t)
#pragma unroll
                for (int r = 0; r < 4; ++r)
                    A2[u][t][r] += bb[t];
#pragma unroll
        for (int s = 0; s < 2; ++s)
#pragma unroll
            for (int t = 0; t < 4; ++t) {
                f16x8 b = *(const f16x8*)&bfrag[((40 + s * 4 + t) * 64 + lane) * 8];
                A2[0][t] = __builtin_amdgcn_mfma_f32_16x16x32_f16(a5[0][s], b, A2[0][t], 0, 0, 0);
                A2[1][t] = __builtin_amdgcn_mfma_f32_16x16x32_f16(a5[1][s], b, A2[1][t], 0, 0, 0);
            }

        // ---- segment max over 8 rows & store (2 y per tile, 4 per pair) ----
#pragma unroll
        for (int u = 0; u < 2; ++u)
#pragma unroll
            for (int t = 0; t < 4; ++t) {
                float pm = fmaxf(fmaxf(A2[u][t][0], A2[u][t][1]),
                                 fmaxf(A2[u][t][2], A2[u][t][3]));
                pm = fmaxf(pm, __shfl_xor(pm, 16, 64));
                if ((q & 1) == 0) {
                    const int y = pr * 4 + u * 2 + (q >> 1);
                    out[(long)y * 64 + t * 16 + n0] = pm;
                }
            }
    }
}

extern "C" void kernel_launch(void* const* d_in, const int* in_sizes, int n_in,
                              void* d_out, int out_size, void* d_ws, size_t ws_size,
                              hipStream_t stream) {
    (void)in_sizes; (void)n_in; (void)ws_size; (void)out_size;
    _Float16* x16 = (_Float16*)d_ws;
    _Float16* d16 = (_Float16*)((char*)d_ws + X16_BYTES);

    prep_x<<<(NX * 16 + 255) / 256, 256, 0, stream>>>((const float*)d_in[0], x16);
    prep_diff<<<(NROWS + 255) / 256, 256, 0, stream>>>(
        (const int*)d_in[3], (const float*)d_in[1], (const float*)d_in[2], d16);

    pointnet_fused<<<512, 512, 0, stream>>>(
        x16, d16,
        (const int*)  d_in[3],   // x_idx
        (const float*)d_in[5],  (const float*)d_in[6],   // W0a, b0a
        (const float*)d_in[7],  (const float*)d_in[8],   // W1a, b1a
        (const float*)d_in[9],                            // Wsa
        (const float*)d_in[10], (const float*)d_in[11],  // W0b, b0b
        (const float*)d_in[12], (const float*)d_in[13],  // W1b, b1b
        (float*)d_out);
}

// Round 9
// 126.458 us; speedup vs baseline: 1.0663x; 1.0663x over previous
//
#include <hip/hip_runtime.h>

// PointNetKnnInterpolator on MI355X (gfx950).
// h = [x[x_idx], pos_x[x_idx]-pos_y[y_idx]]  (400000 x 67)
// net = relu(h)@W0a+b0a ; dx = relu(net)@W1a+b1a ; h2 = h@Wsa + dx
// net2 = relu(h2)@W0b+b0b ; h3 = h2 + relu(net2)@W1b+b1b
// out[y] = max over 8 consecutive rows of h3.
//
// R9: occupancy is the only lever with proven large effect (R2->R3, 8->16
// waves/CU = 1.52x). Push 16->24 waves/CU:
//   - block=768 (12 waves) sharing ONE 48 KB bfrag; LDS 48+27+1=76 KB ->
//     2 blocks/CU = 24 waves/CU (6/SIMD). Grid 512 blocks = 6144 waves.
//   - single tile (16 rows) per wave again: M=32 pairing proved worthless
//     (R6==R3) and single-tile halves register pressure (VGPR cap 85 at 6/EU).
//   - keep prep_x (f16 gather, halved FETCH in R8), DROP prep_diff (~8 us of
//     prep for no main-loop gain) -> diff inline on q==0 as in R6.
//   - stride partition (R7: contiguous partition hurt L2 gather locality).

typedef _Float16 f16x8 __attribute__((ext_vector_type(8)));
typedef _Float16 f16x4 __attribute__((ext_vector_type(4)));
typedef float    f32x4 __attribute__((ext_vector_type(4)));

constexpr int NX      = 20000;
constexpr int NROWS   = 50000 * 8;   // NY * K
constexpr int NTILES  = NROWS / 16;  // 25000
constexpr int NFRAG   = 48;          // 12 W0a + 8 W1a + 12 Wsa + 8 W0b + 8 W1b
constexpr int TSTRIDE = 72;          // halves per row of transition buffer
constexpr int BW      = 12;          // waves per block (block = 768)
constexpr int BLOCK   = 64 * BW;

__global__ void prep_x(const float* __restrict__ x, _Float16* __restrict__ x16) {
    const int i = blockIdx.x * blockDim.x + threadIdx.x;   // one float4 each
    if (i < NX * 16) {
        float4 v = ((const float4*)x)[i];
        f16x4 o = {(_Float16)v.x, (_Float16)v.y, (_Float16)v.z, (_Float16)v.w};
        *(f16x4*)(x16 + (size_t)i * 4) = o;
    }
}

// write relu(acc[4]+bias[4]) in C-layout to tbuf, read back two A-fragments.
// Leading fence orders any previous reads of tbuf before overwrite.
static __device__ __forceinline__ void xpose_relu(const f32x4* acc, const float* bb,
                                                  _Float16* tbuf, int q, int n0,
                                                  f16x8* af) {
    __threadfence_block();
#pragma unroll
    for (int t = 0; t < 4; ++t)
#pragma unroll
        for (int r = 0; r < 4; ++r) {
            float v = acc[t][r] + bb[t];
            tbuf[(q * 4 + r) * TSTRIDE + t * 16 + n0] = (_Float16)(v > 0.0f ? v : 0.0f);
        }
    __threadfence_block();
#pragma unroll
    for (int s = 0; s < 2; ++s)
        af[s] = *(const f16x8*)&tbuf[n0 * TSTRIDE + s * 32 + q * 8];
}

__global__ __launch_bounds__(BLOCK, 6)
void pointnet_fused(const _Float16* __restrict__ x16,
                    const float* __restrict__ pos_x,
                    const float* __restrict__ pos_y,
                    const int*   __restrict__ x_idx,
                    const float* __restrict__ W0a, const float* __restrict__ b0a,
                    const float* __restrict__ W1a, const float* __restrict__ b1a,
                    const float* __restrict__ Wsa,
                    const float* __restrict__ W0b, const float* __restrict__ b0b,
                    const float* __restrict__ W1b, const float* __restrict__ b1b,
                    float* __restrict__ out)
{
    __shared__ __align__(16) _Float16 bfrag[NFRAG * 64 * 8];       // 48 KiB
    __shared__ __align__(16) _Float16 trans[BW][16 * TSTRIDE];     // 27 KiB
    __shared__ float bias_lds[4 * 64];                             // 1 KiB

    const int tid = threadIdx.x;

    // ---- expand weights into B-fragment order (once per block) ----
    for (int p = tid; p < NFRAG * 64; p += BLOCK) {
        const int f = p >> 6;
        const int l = p & 63;
        const float* W; int krows, fl;
        if (f < 12)      { W = W0a; krows = 67; fl = f; }
        else if (f < 20) { W = W1a; krows = 64; fl = f - 12; }
        else if (f < 32) { W = Wsa; krows = 67; fl = f - 20; }
        else if (f < 40) { W = W0b; krows = 64; fl = f - 32; }
        else             { W = W1b; krows = 64; fl = f - 40; }
        const int s = fl >> 2, t = fl & 3;
        const int n = t * 16 + (l & 15);
        const int kbase = s * 32 + (l >> 4) * 8;
        f16x8 v;
#pragma unroll
        for (int j = 0; j < 8; ++j) {
            const int k = kbase + j;
            v[j] = (_Float16)((k < krows) ? W[k * 64 + n] : 0.0f);
        }
        *(f16x8*)&bfrag[p * 8] = v;
    }
    if (tid < 256) {
        const int L = tid >> 6, i = tid & 63;
        const float* b = (L == 0) ? b0a : (L == 1) ? b1a : (L == 2) ? b0b : b1b;
        bias_lds[tid] = b[i];
    }
    __syncthreads();

    const int lane = tid & 63;
    const int wv   = tid >> 6;
    const int n0   = lane & 15;   // C col / A row m
    const int q    = lane >> 4;   // quad

    _Float16* tbuf = trans[wv];
    const int gwave  = blockIdx.x * BW + wv;
    const int nwaves = gridDim.x * BW;

    for (int tile = gwave; tile < NTILES; tile += nwaves) {
        // ---- gather A-side: one 16-row tile, f16 rows (K padded 67->96) ----
        const int row = tile * 16 + n0;
        const int xi  = x_idx[row];
        const _Float16* xp = x16 + (long)xi * 64 + q * 8;
        f16x8 hn[3];
        hn[0] = *(const f16x8*)(xp);
        hn[1] = *(const f16x8*)(xp + 32);
        {
            f16x8 z = {};
            hn[2] = z;
            if (q == 0) {                      // k = 64..66 -> diff dims
                const int yi = row >> 3;
#pragma unroll
                for (int j = 0; j < 3; ++j)
                    hn[2][j] = (_Float16)(pos_x[xi * 3 + j] - pos_y[yi * 3 + j]);
            }
        }

        // ---- mm3 FIRST: A2 = h @ Wsa  (raw hn; frags 20..31) ----
        f32x4 A2[4];
#pragma unroll
        for (int t = 0; t < 4; ++t)
            A2[t] = (f32x4){0.f, 0.f, 0.f, 0.f};
#pragma unroll
        for (int s = 0; s < 3; ++s)
#pragma unroll
            for (int t = 0; t < 4; ++t) {
                f16x8 b = *(const f16x8*)&bfrag[((20 + s * 4 + t) * 64 + lane) * 8];
                A2[t] = __builtin_amdgcn_mfma_f32_16x16x32_f16(hn[s], b, A2[t], 0, 0, 0);
            }

        // ---- relu hn IN PLACE, then mm1: A1 = relu(h) @ W0a (frags 0..11) ----
#pragma unroll
        for (int s = 0; s < 3; ++s)
#pragma unroll
            for (int j = 0; j < 8; ++j) {
                _Float16 v = hn[s][j];
                hn[s][j] = v > (_Float16)0 ? v : (_Float16)0;
            }

        f32x4 A1[4];
#pragma unroll
        for (int t = 0; t < 4; ++t)
            A1[t] = (f32x4){0.f, 0.f, 0.f, 0.f};
#pragma unroll
        for (int s = 0; s < 3; ++s)
#pragma unroll
            for (int t = 0; t < 4; ++t) {
                f16x8 b = *(const f16x8*)&bfrag[((s * 4 + t) * 64 + lane) * 8];
                A1[t] = __builtin_amdgcn_mfma_f32_16x16x32_f16(hn[s], b, A1[t], 0, 0, 0);
            }

        // ---- transpose relu(A1 + b0a) -> a2 frags; mm2: A2 += a2 @ W1a ----
        float bb[4];
#pragma unroll
        for (int t = 0; t < 4; ++t) bb[t] = bias_lds[0 * 64 + t * 16 + n0];
        f16x8 a2f[2];
        xpose_relu(A1, bb, tbuf, q, n0, a2f);
#pragma unroll
        for (int s = 0; s < 2; ++s)
#pragma unroll
            for (int t = 0; t < 4; ++t) {
                f16x8 b = *(const f16x8*)&bfrag[((12 + s * 4 + t) * 64 + lane) * 8];
                A2[t] = __builtin_amdgcn_mfma_f32_16x16x32_f16(a2f[s], b, A2[t], 0, 0, 0);
            }

        // ---- A2 += b1a (h2 complete); transpose relu(A2) -> a4 ----
#pragma unroll
        for (int t = 0; t < 4; ++t) bb[t] = bias_lds[1 * 64 + t * 16 + n0];
#pragma unroll
        for (int t = 0; t < 4; ++t)
#pragma unroll
            for (int r = 0; r < 4; ++r)
                A2[t][r] += bb[t];
        const float bz[4] = {0.f, 0.f, 0.f, 0.f};
        f16x8 a4f[2];
        xpose_relu(A2, bz, tbuf, q, n0, a4f);

        // ---- mm4: A3 = a4 @ W0b (frags 32..39) ----
        f32x4 A3[4];
#pragma unroll
        for (int t = 0; t < 4; ++t)
            A3[t] = (f32x4){0.f, 0.f, 0.f, 0.f};
#pragma unroll
        for (int s = 0; s < 2; ++s)
#pragma unroll
            for (int t = 0; t < 4; ++t) {
                f16x8 b = *(const f16x8*)&bfrag[((32 + s * 4 + t) * 64 + lane) * 8];
                A3[t] = __builtin_amdgcn_mfma_f32_16x16x32_f16(a4f[s], b, A3[t], 0, 0, 0);
            }

        // ---- transpose relu(A3 + b0b) -> a5; mm5: A2 += b1b + a5 @ W1b ----
#pragma unroll
        for (int t = 0; t < 4; ++t) bb[t] = bias_lds[2 * 64 + t * 16 + n0];
        f16x8 a5f[2];
        xpose_relu(A3, bb, tbuf, q, n0, a5f);

#pragma unroll
        for (int t = 0; t < 4; ++t) bb[t] = bias_lds[3 * 64 + t * 16 + n0];
#pragma unroll
        for (int t = 0; t < 4; ++t)
#pragma unroll
            for (int r = 0; r < 4; ++r)
                A2[t][r] += bb[t];
#pragma unroll
        for (int s = 0; s < 2; ++s)
#pragma unroll
            for (int t = 0; t < 4; ++t) {
                f16x8 b = *(const f16x8*)&bfrag[((40 + s * 4 + t) * 64 + lane) * 8];
                A2[t] = __builtin_amdgcn_mfma_f32_16x16x32_f16(a5f[s], b, A2[t], 0, 0, 0);
            }

        // ---- segment max over 8 rows (q0|q1 -> y0, q2|q3 -> y1) & store ----
#pragma unroll
        for (int t = 0; t < 4; ++t) {
            float pm = fmaxf(fmaxf(A2[t][0], A2[t][1]),
                             fmaxf(A2[t][2], A2[t][3]));
            pm = fmaxf(pm, __shfl_xor(pm, 16, 64));
            if ((q & 1) == 0) {
                const int y = tile * 2 + (q >> 1);
                out[(long)y * 64 + t * 16 + n0] = pm;
            }
        }
    }
}

extern "C" void kernel_launch(void* const* d_in, const int* in_sizes, int n_in,
                              void* d_out, int out_size, void* d_ws, size_t ws_size,
                              hipStream_t stream) {
    (void)in_sizes; (void)n_in; (void)ws_size; (void)out_size;
    _Float16* x16 = (_Float16*)d_ws;

    prep_x<<<(NX * 16 + 255) / 256, 256, 0, stream>>>((const float*)d_in[0], x16);

    pointnet_fused<<<512, BLOCK, 0, stream>>>(
        x16,
        (const float*)d_in[1],   // pos_x
        (const float*)d_in[2],   // pos_y
        (const int*)  d_in[3],   // x_idx
        (const float*)d_in[5],  (const float*)d_in[6],   // W0a, b0a
        (const float*)d_in[7],  (const float*)d_in[8],   // W1a, b1a
        (const float*)d_in[9],                            // Wsa
        (const float*)d_in[10], (const float*)d_in[11],  // W0b, b0b
        (const float*)d_in[12], (const float*)d_in[13],  // W1b, b1b
        (float*)d_out);
}

// Round 10
// 121.512 us; speedup vs baseline: 1.1097x; 1.0407x over previous
//
#include <hip/hip_runtime.h>

// PointNetKnnInterpolator on MI355X (gfx950).
// h = [x[x_idx], pos_x[x_idx]-pos_y[y_idx]]  (400000 x 67)
// net = relu(h)@W0a+b0a ; dx = relu(net)@W1a+b1a ; h2 = h@Wsa + dx
// net2 = relu(h2)@W0b+b0b ; h3 = h2 + relu(net2)@W1b+b1b
// out[y] = max over 8 consecutive rows of h3.
//
// R10 STRUCTURAL REWRITE: compute everything transposed (actT_next = WT @ actT,
// weights = A operand from LDS, activations = B operand in registers).
// The MFMA C-layout (lane(n0,q), reg(t,r) = D[feat 16t+4q+r][dr n0]) re-feeds
// the next MFMA's B-frag with ZERO data movement: k-slot k holds feature
// PHI(k) = 32(k>>5)+16((k&7)>>2)+4((k>>3)&3)+(k&3)  (lane-independent bijection)
// and PHI is baked into the WEIGHT LDS layout at fill time. So the 3 mid-chain
// LDS transposes + lgkmcnt(0) fences + 192 scalar ds_write_b16 per tile are
// replaced by 12 VALU (relu + cvt_pk) per transition. Biases fold into K-pads:
// h pad slot (k=67) = 1.0 with W0a row67 = b0a; mm2/mm4/mm5 get an s=2 bias
// fragment (B slot k=64 = 1.0, A row64 = bias). Epilogue: one LDS pass in the
// transposed layout (per-lane b64 writes are CONTIGUOUS here) + b128 reads +
// xor16/xor32 shuffle-max. R6/R8/R9 showed resource scaling is exhausted; this
// attacks the serial chain itself.

typedef _Float16 f16x8 __attribute__((ext_vector_type(8)));
typedef _Float16 f16x4 __attribute__((ext_vector_type(4)));
typedef float    f32x4 __attribute__((ext_vector_type(4)));

constexpr int NX     = 20000;
constexpr int NROWS  = 50000 * 8;    // NY * K
constexpr int NTILES = NROWS / 16;   // 25000
constexpr int NFRAG  = 60;           // 5 matmuls x 12 frags (s=0..2, t=0..3)
constexpr int BW     = 8;            // waves per block
constexpr int BLOCK  = 64 * BW;      // 512
constexpr int TS2    = 72;           // epilogue buffer row stride in f16 (+8 pad)

__global__ void prep_x(const float* __restrict__ x, _Float16* __restrict__ x16) {
    const int i = blockIdx.x * blockDim.x + threadIdx.x;   // one float4 each
    if (i < NX * 16) {
        float4 v = ((const float4*)x)[i];
        f16x4 o = {(_Float16)v.x, (_Float16)v.y, (_Float16)v.z, (_Float16)v.w};
        *(f16x4*)(x16 + (size_t)i * 4) = o;
    }
}

// relu + repack accumulator (C-layout) into the two K=64 B-fragments.
// frag s element j  <->  acc[t=2s+(j>>2)][r=j&3]   (matches PHI weight layout)
static __device__ __forceinline__ void pack_relu(const f32x4* A, f16x8* bf) {
#pragma unroll
    for (int s = 0; s < 2; ++s) {
        f16x8 r;
#pragma unroll
        for (int e = 0; e < 8; ++e) {
            float v = A[2 * s + (e >> 2)][e & 3];
            r[e] = (_Float16)(v > 0.0f ? v : 0.0f);
        }
        bf[s] = r;
    }
}

__global__ __launch_bounds__(BLOCK, 4)
void pointnet_fused(const _Float16* __restrict__ x16,
                    const float* __restrict__ pos_x,
                    const float* __restrict__ pos_y,
                    const int*   __restrict__ x_idx,
                    const float* __restrict__ W0a, const float* __restrict__ b0a,
                    const float* __restrict__ W1a, const float* __restrict__ b1a,
                    const float* __restrict__ Wsa,
                    const float* __restrict__ W0b, const float* __restrict__ b0b,
                    const float* __restrict__ W1b, const float* __restrict__ b1b,
                    float* __restrict__ out)
{
    __shared__ __align__(16) _Float16 bfrag[NFRAG * 64 * 8];   // 60 KiB
    __shared__ __align__(16) _Float16 ebuf[BW][16 * TS2];      // 18 KiB

    const int tid = threadIdx.x;

    // ---- fill weight fragments (A operands, transposed; PHI-permuted K) ----
    // groups: 0=W0a(identity,+b0a@k67) 1=Wsa(identity) 2=W1a(PHI,+b1a@k64)
    //         3=W0b(PHI,+b0b@k64) 4=W1b(PHI,+b1b@k64)
    for (int p = tid; p < NFRAG * 64; p += BLOCK) {
        const int f = p >> 6, l = p & 63;
        const int q = l >> 4, n0 = l & 15;
        const int grp = f / 12, fl = f % 12, s = fl >> 2, t = fl & 3;
        const int col = t * 16 + n0;
        f16x8 v;
#pragma unroll
        for (int j = 0; j < 8; ++j) {
            const int k = 32 * s + 8 * q + j;
            float val = 0.0f;
            if (grp == 0)      val = (k < 67) ? W0a[k * 64 + col] : (k == 67 ? b0a[col] : 0.0f);
            else if (grp == 1) val = (k < 67) ? Wsa[k * 64 + col] : 0.0f;
            else {
                const float* W  = (grp == 2) ? W1a : (grp == 3) ? W0b : W1b;
                const float* bb = (grp == 2) ? b1a : (grp == 3) ? b0b : b1b;
                if (s < 2) {
                    const int row = 32 * s + 16 * (j >> 2) + 4 * q + (j & 3);  // PHI(k)
                    val = W[row * 64 + col];
                } else {
                    val = (q == 0 && j == 0) ? bb[col] : 0.0f;   // bias slot k=64
                }
            }
            v[j] = (_Float16)val;
        }
        *(f16x8*)&bfrag[p * 8] = v;
    }
    __syncthreads();

    const int lane = tid & 63;
    const int wv   = tid >> 6;
    const int n0   = lane & 15;   // B col = data row (dr) / A row m = out-feat
    const int q    = lane >> 4;

    _Float16* eb = ebuf[wv];

    // constant bias B-fragment: slot k=64 (q==0, j==0) = 1.0
    f16x8 bfr = {};
    if (q == 0) bfr[0] = (_Float16)1.0f;

    // epilogue lane roles
    const int ey  = (lane >> 3) & 1;   // y within tile
    const int efg = lane & 7;          // feature group of 8
    const int esb = lane >> 4;         // sub: covers 2 drs

    const int gwave  = blockIdx.x * BW + wv;
    const int nwaves = gridDim.x * BW;

#define WFRAG(fid) (*(const f16x8*)&bfrag[(((fid) * 64) + lane) * 8])

    for (int tile = gwave; tile < NTILES; tile += nwaves) {
        // ---- gather h^T B-frags: lane(n0,q) = h[dr=n0][feats 32s+8q+j] ----
        const int row = tile * 16 + n0;
        const int xi  = x_idx[row];
        const _Float16* xp = x16 + (long)xi * 64 + q * 8;
        f16x8 hn[3];
        hn[0] = *(const f16x8*)(xp);
        hn[1] = *(const f16x8*)(xp + 32);
        {
            f16x8 z = {};
            hn[2] = z;
            if (q == 0) {                      // k=64..66 diff, k=67 = 1.0 (bias hook)
                const int yi = row >> 3;
#pragma unroll
                for (int j = 0; j < 3; ++j)
                    hn[2][j] = (_Float16)(pos_x[xi * 3 + j] - pos_y[yi * 3 + j]);
                hn[2][3] = (_Float16)1.0f;
            }
        }

        // ---- mm3 first (raw h): A2 = (h @ Wsa)^T ----
        f32x4 A2[4];
#pragma unroll
        for (int t = 0; t < 4; ++t) A2[t] = (f32x4){0.f, 0.f, 0.f, 0.f};
#pragma unroll
        for (int s = 0; s < 3; ++s)
#pragma unroll
            for (int t = 0; t < 4; ++t)
                A2[t] = __builtin_amdgcn_mfma_f32_16x16x32_f16(WFRAG(12 + s * 4 + t), hn[s], A2[t], 0, 0, 0);

        // ---- relu h in place (pad 1.0 survives); mm1: A1 = net^T (+b0a via k67) ----
#pragma unroll
        for (int s = 0; s < 3; ++s)
#pragma unroll
            for (int j = 0; j < 8; ++j) {
                _Float16 v = hn[s][j];
                hn[s][j] = v > (_Float16)0 ? v : (_Float16)0;
            }
        f32x4 A1[4];
#pragma unroll
        for (int t = 0; t < 4; ++t) A1[t] = (f32x4){0.f, 0.f, 0.f, 0.f};
#pragma unroll
        for (int s = 0; s < 3; ++s)
#pragma unroll
            for (int t = 0; t < 4; ++t)
                A1[t] = __builtin_amdgcn_mfma_f32_16x16x32_f16(WFRAG(s * 4 + t), hn[s], A1[t], 0, 0, 0);

        // ---- mm2: A2 += (relu(net) @ W1a)^T + b1a   (B = repacked A1, no LDS) ----
        f16x8 bf[2];
        pack_relu(A1, bf);
#pragma unroll
        for (int t = 0; t < 4; ++t) {
            A2[t] = __builtin_amdgcn_mfma_f32_16x16x32_f16(WFRAG(24 + 0 * 4 + t), bf[0], A2[t], 0, 0, 0);
            A2[t] = __builtin_amdgcn_mfma_f32_16x16x32_f16(WFRAG(24 + 1 * 4 + t), bf[1], A2[t], 0, 0, 0);
            A2[t] = __builtin_amdgcn_mfma_f32_16x16x32_f16(WFRAG(24 + 2 * 4 + t), bfr,   A2[t], 0, 0, 0);
        }

        // ---- mm4: A3 = (relu(h2) @ W0b)^T + b0b ----
        pack_relu(A2, bf);
        f32x4 A3[4];
#pragma unroll
        for (int t = 0; t < 4; ++t) A3[t] = (f32x4){0.f, 0.f, 0.f, 0.f};
#pragma unroll
        for (int t = 0; t < 4; ++t) {
            A3[t] = __builtin_amdgcn_mfma_f32_16x16x32_f16(WFRAG(36 + 0 * 4 + t), bf[0], A3[t], 0, 0, 0);
            A3[t] = __builtin_amdgcn_mfma_f32_16x16x32_f16(WFRAG(36 + 1 * 4 + t), bf[1], A3[t], 0, 0, 0);
            A3[t] = __builtin_amdgcn_mfma_f32_16x16x32_f16(WFRAG(36 + 2 * 4 + t), bfr,   A3[t], 0, 0, 0);
        }

        // ---- mm5: A2 += (relu(net2) @ W1b)^T + b1b   -> h3^T ----
        pack_relu(A3, bf);
#pragma unroll
        for (int t = 0; t < 4; ++t) {
            A2[t] = __builtin_amdgcn_mfma_f32_16x16x32_f16(WFRAG(48 + 0 * 4 + t), bf[0], A2[t], 0, 0, 0);
            A2[t] = __builtin_amdgcn_mfma_f32_16x16x32_f16(WFRAG(48 + 1 * 4 + t), bf[1], A2[t], 0, 0, 0);
            A2[t] = __builtin_amdgcn_mfma_f32_16x16x32_f16(WFRAG(48 + 2 * 4 + t), bfr,   A2[t], 0, 0, 0);
        }

        // ---- epilogue: h3^T -> ebuf[dr][feat] (b64 writes, contiguous here) ----
        __threadfence_block();
#pragma unroll
        for (int t = 0; t < 4; ++t) {
            f16x4 w;
#pragma unroll
            for (int r = 0; r < 4; ++r) w[r] = (_Float16)A2[t][r];
            *(f16x4*)&eb[n0 * TS2 + t * 16 + q * 4] = w;   // feat = 16t+4q+r
        }
        __threadfence_block();

        // read 2 drs x 8 feats, max-reduce over 8 drs via xor16/xor32 shuffles
        const int dr0 = ey * 8 + esb * 2;
        f16x8 ra = *(const f16x8*)&eb[dr0 * TS2 + efg * 8];
        f16x8 rb = *(const f16x8*)&eb[(dr0 + 1) * TS2 + efg * 8];
#pragma unroll
        for (int e = 0; e < 8; ++e) ra[e] = ra[e] > rb[e] ? ra[e] : rb[e];
#pragma unroll
        for (int st = 0; st < 2; ++st) {
            union { f16x8 h; int i[4]; } u, v2;
            u.h = ra;
#pragma unroll
            for (int d = 0; d < 4; ++d) v2.i[d] = __shfl_xor(u.i[d], st == 0 ? 16 : 32, 64);
#pragma unroll
            for (int e = 0; e < 8; ++e) ra[e] = ra[e] > v2.h[e] ? ra[e] : v2.h[e];
        }
        if (esb == 0) {
            float4 f0 = {(float)ra[0], (float)ra[1], (float)ra[2], (float)ra[3]};
            float4 f1 = {(float)ra[4], (float)ra[5], (float)ra[6], (float)ra[7]};
            float* op = out + (long)(tile * 2 + ey) * 64 + efg * 8;
            *(float4*)op = f0;
            *(float4*)(op + 4) = f1;
        }
    }
#undef WFRAG
}

extern "C" void kernel_launch(void* const* d_in, const int* in_sizes, int n_in,
                              void* d_out, int out_size, void* d_ws, size_t ws_size,
                              hipStream_t stream) {
    (void)in_sizes; (void)n_in; (void)ws_size; (void)out_size;
    _Float16* x16 = (_Float16*)d_ws;

    prep_x<<<(NX * 16 + 255) / 256, 256, 0, stream>>>((const float*)d_in[0], x16);

    pointnet_fused<<<512, BLOCK, 0, stream>>>(
        x16,
        (const float*)d_in[1],   // pos_x
        (const float*)d_in[2],   // pos_y
        (const int*)  d_in[3],   // x_idx
        (const float*)d_in[5],  (const float*)d_in[6],   // W0a, b0a
        (const float*)d_in[7],  (const float*)d_in[8],   // W1a, b1a
        (const float*)d_in[9],                            // Wsa
        (const float*)d_in[10], (const float*)d_in[11],  // W0b, b0b
        (const float*)d_in[12], (const float*)d_in[13],  // W1b, b1b
        (float*)d_out);
}